// Round 3
// baseline (246.049 us; speedup 1.0000x reference)
//
#include <hip/hip_runtime.h>
#include <math.h>

#define BATCH 256
#define FB    64
#define NCOL  147456          // 128*128*3*3
#define NCOL4 (NCOL / 4)      // 36864 float4 columns
#define TPB   256
#define BT    16              // batch tile per block
#define NBG   (BATCH / BT)    // 16 batch groups
#define NXB   (NCOL / (TPB * 4))  // 144 column blocks
#define PTS   (BT + 4)        // padded LDS row stride: 20 floats = 80B, 16B-aligned,
                              // bank = (20*lane + r)%32 -> 8 lanes/bank (vs 64-way unpadded)

// NOTE: parameter names must not collide with the .x/.y/.z/.w member tokens
// (a param named `w` would turn `(A).w` into `(A).<arg>` — round-2 compile bug).
#define FMA4(A, S, WV) do { \
    (A).x = fmaf((S), (WV).x, (A).x); \
    (A).y = fmaf((S), (WV).y, (A).y); \
    (A).z = fmaf((S), (WV).z, (A).z); \
    (A).w = fmaf((S), (WV).w, (A).w); \
} while (0)

// Fused softmax + bank-weighted GEMM.
// out[b][n] = sum_f softmax(x)[b][f] * W[f][n]
// Block: 256 threads x float4 = 1024 cols, 16-batch tile.
// Grid: (144, 16) = 2304 blocks = 9 per CU exactly (balanced).
__global__ __launch_bounds__(TPB, 4) void bank_gemm_fused(
        const float* __restrict__ W, const float* __restrict__ X,
        float* __restrict__ out) {
    __shared__ float pt[FB * PTS];   // pt[f*PTS + b]  (transposed probs tile)

    const int tid = threadIdx.x;

    // XCD-chunked swizzle: make the 16 batch-group partners of one column
    // block consecutive on a single XCD (dispatch round-robins wg%8 across
    // XCDs). Each XCD then reads a W column-slice into its L2 once and
    // reuses it 16x, instead of every partner missing to L3.
    const int wg   = blockIdx.y * gridDim.x + blockIdx.x;  // 0..2303
    const int xcd  = wg & 7;
    const int slot = wg >> 3;                 // 0..287 (per-XCD sequence)
    const int bx   = xcd * (NXB / 8) + (slot >> 4);  // column block 0..143
    const int bg   = slot & 15;               // batch group 0..15 (fastest)

    const float4* Wv = (const float4*)W;
    const int c4 = bx * TPB + tid;            // this thread's float4 column

    // 4-deep weight prefetch ring: issue before the softmax prologue so the
    // HBM/L2 latency hides under the shuffle-reduce work, and the main loop
    // keeps 4 loads in flight (counted vmcnt, never drained to 0).
    float4 wr0 = Wv[0 * NCOL4 + c4];
    float4 wr1 = Wv[1 * NCOL4 + c4];
    float4 wr2 = Wv[2 * NCOL4 + c4];
    float4 wr3 = Wv[3 * NCOL4 + c4];

    // Fused softmax: FB == wave width (64). 4 waves x 4 rows = 16 rows.
    const int wave = tid >> 6;
    const int lane = tid & 63;
#pragma unroll
    for (int r0 = 0; r0 < BT / 4; ++r0) {
        const int r = r0 * 4 + wave;
        float v = X[(bg * BT + r) * FB + lane];
        float m = v;
#pragma unroll
        for (int o = 32; o > 0; o >>= 1) m = fmaxf(m, __shfl_xor(m, o));
        float e = __expf(v - m);
        float s = e;
#pragma unroll
        for (int o = 32; o > 0; o >>= 1) s += __shfl_xor(s, o);
        pt[lane * PTS + r] = e / s;   // padded stride: 8-way not 64-way conflict
    }
    __syncthreads();

    float4 acc[BT];
#pragma unroll
    for (int b = 0; b < BT; ++b) acc[b] = make_float4(0.f, 0.f, 0.f, 0.f);

    // Main K loop, hand-unrolled x4 so the ring indices are static (no
    // scratch) and the compiler emits counted s_waitcnt vmcnt(3).
#define STEP(J, WREG) do { \
        const float4 wcur = (WREG); \
        (WREG) = Wv[(f + 4 + (J)) * NCOL4 + c4]; \
        const float4* p4 = (const float4*)&pt[(f + (J)) * PTS]; \
        _Pragma("unroll") \
        for (int q = 0; q < BT / 4; ++q) { \
            const float4 p = p4[q];   /* uniform-address LDS broadcast */ \
            FMA4(acc[4 * q + 0], p.x, wcur); \
            FMA4(acc[4 * q + 1], p.y, wcur); \
            FMA4(acc[4 * q + 2], p.z, wcur); \
            FMA4(acc[4 * q + 3], p.w, wcur); \
        } \
    } while (0)

#define TAIL(J, WREG) do { \
        const float4 wcur = (WREG); \
        const float4* p4 = (const float4*)&pt[(f + (J)) * PTS]; \
        _Pragma("unroll") \
        for (int q = 0; q < BT / 4; ++q) { \
            const float4 p = p4[q]; \
            FMA4(acc[4 * q + 0], p.x, wcur); \
            FMA4(acc[4 * q + 1], p.y, wcur); \
            FMA4(acc[4 * q + 2], p.z, wcur); \
            FMA4(acc[4 * q + 3], p.w, wcur); \
        } \
    } while (0)

    for (int f = 0; f < FB - 4; f += 4) {
        STEP(0, wr0);
        STEP(1, wr1);
        STEP(2, wr2);
        STEP(3, wr3);
    }
    {
        const int f = FB - 4;   // 60..63: drain the ring, no more loads
        TAIL(0, wr0);
        TAIL(1, wr1);
        TAIL(2, wr2);
        TAIL(3, wr3);
    }
#undef STEP
#undef TAIL

    // Coalesced float4 stores.
    float4* Ov = (float4*)out;
    const int obase = (bg * BT) * NCOL4 + c4;
#pragma unroll
    for (int b = 0; b < BT; ++b) {
        Ov[obase + b * NCOL4] = acc[b];
    }
}

extern "C" void kernel_launch(void* const* d_in, const int* in_sizes, int n_in,
                              void* d_out, int out_size, void* d_ws, size_t ws_size,
                              hipStream_t stream) {
    const float* bank   = (const float*)d_in[0];   // (256, 64)
    const float* weight = (const float*)d_in[1];   // (64, 128,128,3,3)
    float* out   = (float*)d_out;                  // (256, 147456)
    (void)d_ws; (void)ws_size;

    dim3 grid(NXB, NBG);
    bank_gemm_fused<<<grid, TPB, 0, stream>>>(weight, bank, out);
}

// Round 5
// 224.901 us; speedup vs baseline: 1.0940x; 1.0940x over previous
//
#include <hip/hip_runtime.h>
#include <math.h>

#define BATCH 256
#define FB    64
#define NCOL  147456              // 128*128*3*3
#define NCOL4 (NCOL / 4)          // 36864 float4 columns
#define TPB   256
#define BT    32                  // batch tile per block (acc = 128 VGPRs)
#define NBG   (BATCH / BT)        // 8 batch groups
#define NXB   (NCOL / (TPB * 4))  // 144 column blocks

// Native clang vector type: __builtin_nontemporal_store rejects
// HIP_vector_type<float,4> (round-4 compile bug) but accepts this.
typedef float f4 __attribute__((ext_vector_type(4)));

// Param names must not collide with .x/.y/.z/.w member tokens (round-2 bug).
#define FMA4(A, S, WV) do { \
    (A).x = fmaf((S), (WV).x, (A).x); \
    (A).y = fmaf((S), (WV).y, (A).y); \
    (A).z = fmaf((S), (WV).z, (A).z); \
    (A).w = fmaf((S), (WV).w, (A).w); \
} while (0)

// One wave (64 lanes == FB) per batch row; writes TRANSPOSED probs P^T[f][b]
// so the GEMM reads 32 consecutive floats per filter at a wave-uniform
// address (-> scalar s_load into SGPRs).
__global__ void softmax_t(const float* __restrict__ x, float* __restrict__ pt) {
    const int b = blockIdx.x;
    const int lane = threadIdx.x;
    float v = x[b * FB + lane];
    float m = v;
#pragma unroll
    for (int o = 32; o > 0; o >>= 1) m = fmaxf(m, __shfl_xor(m, o));
    float e = __expf(v - m);
    float s = e;
#pragma unroll
    for (int o = 32; o > 0; o >>= 1) s += __shfl_xor(s, o);
    pt[lane * BATCH + b] = e / s;   // P^T: (FB, BATCH)
}

// out[b][n] = sum_f P^T[f][b] * W[f][n]
// Probs are BLOCK-UNIFORM -> read at wave-uniform addresses so they live in
// SGPRs (scalar cache), and the inner op is v_fmac_f32 vacc, s_p, v_w.
// No LDS at all. 4-deep W prefetch ring (counted vmcnt). BT=32 keeps the
// 128-reg accumulator; launch_bounds(256,2) caps at 256 regs -> NO spills
// (round 3 lesson: capping to 128 spilled to scratch, +20 MB HBM writes).
__global__ __launch_bounds__(TPB, 2) void bank_gemm(
        const float* __restrict__ W, const float* __restrict__ Pt,
        float* __restrict__ out) {
    const int tid = threadIdx.x;

    // XCD-chunked swizzle (kept from round 3: it halved FETCH_SIZE).
    // The 8 batch-group partners of one column block become consecutive on a
    // single XCD -> its L2 reads that W slice once, reuses it 8x.
    const int wg   = blockIdx.y * gridDim.x + blockIdx.x;  // 0..1151
    const int xcd  = wg & 7;
    const int slot = wg >> 3;                              // 0..143
    const int bx   = xcd * (NXB / 8) + (slot >> 3);        // column block
    const int bg   = slot & (NBG - 1);                     // batch group (fastest)

    const float4* Wv = (const float4*)W;
    const int c4 = bx * TPB + tid;   // this thread's float4 column

    // 4-deep weight prefetch ring.
    float4 wr0 = Wv[0 * NCOL4 + c4];
    float4 wr1 = Wv[1 * NCOL4 + c4];
    float4 wr2 = Wv[2 * NCOL4 + c4];
    float4 wr3 = Wv[3 * NCOL4 + c4];

    float4 acc[BT];
#pragma unroll
    for (int b = 0; b < BT; ++b) acc[b] = make_float4(0.f, 0.f, 0.f, 0.f);

    // Hand-unrolled x4 ring so indices are static (no scratch) and the
    // compiler emits counted s_waitcnt vmcnt(3), never draining to 0.
#define STEP(J, WREG) do { \
        const float4 wcur = (WREG); \
        (WREG) = Wv[(f + 4 + (J)) * NCOL4 + c4]; \
        const float* pr = Pt + (f + (J)) * BATCH + bg * BT; \
        _Pragma("unroll") \
        for (int q = 0; q < BT / 4; ++q) { \
            const float4 pq = *(const float4*)(pr + 4 * q); /* uniform -> s_load */ \
            FMA4(acc[4 * q + 0], pq.x, wcur); \
            FMA4(acc[4 * q + 1], pq.y, wcur); \
            FMA4(acc[4 * q + 2], pq.z, wcur); \
            FMA4(acc[4 * q + 3], pq.w, wcur); \
        } \
    } while (0)

#define TAIL(J, WREG) do { \
        const float4 wcur = (WREG); \
        const float* pr = Pt + (f + (J)) * BATCH + bg * BT; \
        _Pragma("unroll") \
        for (int q = 0; q < BT / 4; ++q) { \
            const float4 pq = *(const float4*)(pr + 4 * q); \
            FMA4(acc[4 * q + 0], pq.x, wcur); \
            FMA4(acc[4 * q + 1], pq.y, wcur); \
            FMA4(acc[4 * q + 2], pq.z, wcur); \
            FMA4(acc[4 * q + 3], pq.w, wcur); \
        } \
    } while (0)

    for (int f = 0; f < FB - 4; f += 4) {
        STEP(0, wr0);
        STEP(1, wr1);
        STEP(2, wr2);
        STEP(3, wr3);
    }
    {
        const int f = FB - 4;   // 60..63: drain the ring, no more loads
        TAIL(0, wr0);
        TAIL(1, wr1);
        TAIL(2, wr2);
        TAIL(3, wr3);
    }
#undef STEP
#undef TAIL

    // Non-temporal float4 stores: the 151 MB output is write-once, never
    // re-read -> keep it from evicting the per-XCD W slice (~4.6 MB) from L2.
    f4* Ov = (f4*)out;
    const int obase = (bg * BT) * NCOL4 + c4;
#pragma unroll
    for (int b = 0; b < BT; ++b) {
        f4 val;
        val.x = acc[b].x; val.y = acc[b].y; val.z = acc[b].z; val.w = acc[b].w;
        __builtin_nontemporal_store(val, &Ov[obase + b * NCOL4]);
    }
}

extern "C" void kernel_launch(void* const* d_in, const int* in_sizes, int n_in,
                              void* d_out, int out_size, void* d_ws, size_t ws_size,
                              hipStream_t stream) {
    const float* bank   = (const float*)d_in[0];   // (256, 64)
    const float* weight = (const float*)d_in[1];   // (64, 128,128,3,3)
    float* out   = (float*)d_out;                  // (256, 147456)
    float* probsT = (float*)d_ws;                  // P^T: 64*256 fp32 = 64 KB

    softmax_t<<<BATCH, FB, 0, stream>>>(bank, probsT);

    dim3 grid(NXB, NBG);
    bank_gemm<<<grid, TPB, 0, stream>>>(weight, probsT, out);
}

// Round 7
// 205.251 us; speedup vs baseline: 1.1988x; 1.0957x over previous
//
#include <hip/hip_runtime.h>
#include <math.h>

#define BATCH 256
#define FB    64
#define NCOL  147456              // 128*128*3*3
#define TPB   256
#define MT    32                  // batch rows per block
#define NTB   512                 // cols per block
#define NXB   (NCOL / NTB)        // 288 column blocks
#define NBG   (BATCH / MT)        // 8 batch groups

// MFMA fragment types (guide-verified short8 signature for gfx950 bf16 MFMA).
typedef __attribute__((ext_vector_type(8))) short bf16x8;
typedef __attribute__((ext_vector_type(4))) float f32x4;

// hi = truncate-to-bf16 (top 16 bits); lo = exact fp32 residual, re-truncated.
// out = Ph*Wh + Ph*Wl + Pl*Wh reproduces fp32 to ~2^-16 rel (dropped Pl*Wl).
__device__ __forceinline__ short bhi(float x) {
    return (short)(__float_as_uint(x) >> 16);
}
__device__ __forceinline__ float fhi(float x) {
    return __uint_as_float(__float_as_uint(x) & 0xffff0000u);
}

// One wave (64 lanes == FB) per batch row -> row-major probs P[b][f].
__global__ void softmax_rows(const float* __restrict__ x, float* __restrict__ p) {
    const int b = blockIdx.x;
    const int lane = threadIdx.x;
    float v = x[b * FB + lane];
    float m = v;
#pragma unroll
    for (int o = 32; o > 0; o >>= 1) m = fmaxf(m, __shfl_xor(m, o));
    float e = __expf(v - m);
    float s = e;
#pragma unroll
    for (int o = 32; o > 0; o >>= 1) s += __shfl_xor(s, o);
    p[b * FB + lane] = e / s;
}

// Split-bf16 MFMA GEMM: out[b][n] = sum_f P[b][f] * W[f][n], K=64.
// Block: 4 waves, 32 rows x 512 cols. Wave w: rows {0..31}, cols w*128..+128
// = 2 row-tiles x 8 col-tiles of 16x16. 12 MFMA per col-tile (3 products x
// 2 K-steps x 2 row-tiles shared-B). Fragment layout (m89/m91-verified):
//   A: row=lane&15, k=(lane>>4)*8+i   B: col=lane&15, k=(lane>>4)*8+i
//   C/D: col=lane&15, row=(lane>>4)*4+reg
__global__ __launch_bounds__(TPB, 2) void bank_gemm_mfma(
        const float* __restrict__ W, const float* __restrict__ P,
        float* __restrict__ out) {
    const int tid  = threadIdx.x;
    const int wv   = tid >> 6;        // wave 0..3
    const int lane = tid & 63;
    const int kg   = lane >> 4;       // k-group 0..3
    const int lr   = lane & 15;

    // XCD-chunked swizzle (kept: halves FETCH_SIZE). 8 batch-group partners
    // of one column block run consecutively on one XCD -> W slice L2-resident.
    const int wg   = blockIdx.y * gridDim.x + blockIdx.x;  // 0..2303
    const int xcd  = wg & 7;
    const int slot = wg >> 3;                              // 0..287
    const int bx   = xcd * (NXB / 8) + (slot >> 3);        // column block 0..287
    const int bg   = slot & (NBG - 1);                     // batch group 0..7

    const int row0 = bg * MT;
    const int col0 = bx * NTB + wv * 128;

    // ---- A fragments: probs hi/lo, [row-tile][K-step]. 8 consecutive f per
    // lane -> two aligned float4 loads per fragment.
    bf16x8 pah[2][2], pal[2][2];
#pragma unroll
    for (int rt = 0; rt < 2; ++rt) {
#pragma unroll
        for (int s = 0; s < 2; ++s) {
            const float* pr = P + (row0 + rt * 16 + lr) * FB + s * 32 + kg * 8;
            float av[8];
            *(f32x4*)&av[0] = *(const f32x4*)pr;
            *(f32x4*)&av[4] = *(const f32x4*)(pr + 4);
#pragma unroll
            for (int i = 0; i < 8; ++i) {
                const float xx = av[i];
                pah[rt][s][i] = bhi(xx);
                pal[rt][s][i] = bhi(xx - fhi(xx));
            }
        }
    }

    f32x4 acc[2][8];
#pragma unroll
    for (int rt = 0; rt < 2; ++rt)
#pragma unroll
        for (int t = 0; t < 8; ++t)
            acc[rt][t] = (f32x4){0.f, 0.f, 0.f, 0.f};

    // ---- Main loop over this wave's 8 col-tiles. B gathered straight from
    // W (fp32) in L2: lane reads W[s*32+kg*8+i][col], 16-lane groups give
    // 64B-coalesced segments. Fully unrolled (static acc indices, rule #20).
    const float* wbase = W + (kg * 8) * NCOL + col0 + lr;
#pragma unroll
    for (int t = 0; t < 8; ++t) {
        const float* wp = wbase + t * 16;
        float wv0[8], wv1[8];
#pragma unroll
        for (int i = 0; i < 8; ++i) {
            wv0[i] = wp[i * NCOL];            // K-step 0: f = kg*8 + i
            wv1[i] = wp[(32 + i) * NCOL];     // K-step 1: f = 32 + kg*8 + i
        }
        bf16x8 wh0, wl0, wh1, wl1;
#pragma unroll
        for (int i = 0; i < 8; ++i) {
            wh0[i] = bhi(wv0[i]); wl0[i] = bhi(wv0[i] - fhi(wv0[i]));
            wh1[i] = bhi(wv1[i]); wl1[i] = bhi(wv1[i] - fhi(wv1[i]));
        }
#pragma unroll
        for (int rt = 0; rt < 2; ++rt) {
            f32x4 c = acc[rt][t];
            c = __builtin_amdgcn_mfma_f32_16x16x32_bf16(pah[rt][0], wh0, c, 0, 0, 0);
            c = __builtin_amdgcn_mfma_f32_16x16x32_bf16(pah[rt][1], wh1, c, 0, 0, 0);
            c = __builtin_amdgcn_mfma_f32_16x16x32_bf16(pah[rt][0], wl0, c, 0, 0, 0);
            c = __builtin_amdgcn_mfma_f32_16x16x32_bf16(pah[rt][1], wl1, c, 0, 0, 0);
            c = __builtin_amdgcn_mfma_f32_16x16x32_bf16(pal[rt][0], wh0, c, 0, 0, 0);
            c = __builtin_amdgcn_mfma_f32_16x16x32_bf16(pal[rt][1], wh1, c, 0, 0, 0);
            acc[rt][t] = c;
        }
    }

    // ---- Epilogue: C/D fragment stores. Per store instr, lanes 0-15 write
    // 64B contiguous (rows differ per kg group); adjacent col-tiles merge in L2.
#pragma unroll
    for (int rt = 0; rt < 2; ++rt)
#pragma unroll
        for (int t = 0; t < 8; ++t)
#pragma unroll
            for (int r = 0; r < 4; ++r)
                out[(size_t)(row0 + rt * 16 + kg * 4 + r) * NCOL
                    + col0 + t * 16 + lr] = acc[rt][t][r];
}

extern "C" void kernel_launch(void* const* d_in, const int* in_sizes, int n_in,
                              void* d_out, int out_size, void* d_ws, size_t ws_size,
                              hipStream_t stream) {
    const float* bank   = (const float*)d_in[0];   // (256, 64)
    const float* weight = (const float*)d_in[1];   // (64, 128,128,3,3)
    float* out   = (float*)d_out;                  // (256, 147456)
    float* probs = (float*)d_ws;                   // 256*64 fp32 = 64 KB

    softmax_rows<<<BATCH, FB, 0, stream>>>(bank, probs);

    dim3 grid(NXB, NBG);   // (288, 8) = 2304 blocks
    bank_gemm_mfma<<<grid, TPB, 0, stream>>>(weight, probs, out);
}